// Round 18
// baseline (5172.139 us; speedup 1.0000x reference)
//
#include <hip/hip_runtime.h>
#include <hip/hip_bf16.h>

#define TT 127
#define L2E 1.4426950408889634f

typedef __attribute__((ext_vector_type(8))) short s8v;
typedef __attribute__((ext_vector_type(4))) float f4v;
typedef __attribute__((ext_vector_type(4))) int i4v;

__device__ __forceinline__ float bf2f(unsigned short u){
  union { unsigned int i; float f; } v; v.i = ((unsigned int)u) << 16; return v.f;
}
__device__ __forceinline__ unsigned short f2bf(float f){
  union { float f; unsigned int i; } v; v.f = f;
  unsigned int r = v.i + 0x7FFFu + ((v.i >> 16) & 1u);
  return (unsigned short)(r >> 16);
}
__device__ __forceinline__ float fexp2(float x){ return __builtin_amdgcn_exp2f(x); }
__device__ __forceinline__ float frcp(float x){ return __builtin_amdgcn_rcpf(x); }
__device__ __forceinline__ float sigm(float x){
  return frcp(1.f + fexp2(-L2E * x));
}
__device__ __forceinline__ float tanh_f(float x){
  return 1.f - 2.f * frcp(1.f + fexp2(2.f * L2E * x));
}
__device__ __forceinline__ f4v mfma16(s8v a, s8v b, f4v c){
  return __builtin_amdgcn_mfma_f32_16x16x32_bf16(a, b, c, 0, 0, 0);
}
__device__ __forceinline__ void barrier_lgkm(){
  asm volatile("s_waitcnt lgkmcnt(0)" ::: "memory");
  __builtin_amdgcn_s_barrier();
}

// ---------- prep: pack weights chunk-major (48 chunks x 16KB = [f][w][lane][16B]) ----------
__global__ void k_pack_w1dc(const float* __restrict__ W1, unsigned short* __restrict__ WP){
  int n = blockIdx.x * 256 + threadIdx.x;   // 16384 = [kt][w][lane]
  int lane = n & 63, w = (n >> 6) & 15, kt = n >> 10;
  int h = w * 16 + (lane & 15);
  int i0 = kt * 32 + (lane >> 4) * 8;
  #pragma unroll
  for (int j = 0; j < 8; ++j)
    WP[(size_t)n * 8 + j] = f2bf(W1[h * 768 + i0 + j]);
}
__global__ void k_pack_whh(const float* __restrict__ Whh, unsigned short* __restrict__ WP){
  int n = blockIdx.x * 256 + threadIdx.x;   // 32768 = [f][w][lane]
  int lane = n & 63, w = (n >> 6) & 15, f = n >> 10;
  int ct = f >> 3, kt = f & 7;
  int g = (w * 4 + ct) * 16 + (lane & 15);
  int i0 = kt * 32 + (lane >> 4) * 8;
  #pragma unroll
  for (int j = 0; j < 8; ++j)
    WP[131072 + (size_t)n * 8 + j] = f2bf(Whh[g * 256 + i0 + j]);
}

__global__ void k_tr_w1x(const float* __restrict__ W1, float* __restrict__ W1xT){
  int idx = blockIdx.x * 256 + threadIdx.x;   // 256*256
  int k = idx >> 8, h = idx & 255;
  W1xT[idx] = W1[h * 768 + 512 + k];
}

// ---------- prep: xf[b,t] = X[b,t,:]·fcW[0:256], xg[b,t] = X[b,t,:]·fcfW[256:512] ----------
__global__ void k_xfg(const float* __restrict__ X, const float* __restrict__ fcW,
                      const float* __restrict__ fcfW,
                      float* __restrict__ xf, float* __restrict__ xg){
  const int b = blockIdx.x;
  const int w = threadIdx.x >> 6, lane = threadIdx.x & 63;
  f4v wf = *(const f4v*)&fcW[lane * 4];
  f4v wg = *(const f4v*)&fcfW[256 + lane * 4];
  for (int t = w; t < TT; t += 4) {
    f4v x = *(const f4v*)&X[((size_t)b * TT + t) * 256 + lane * 4];
    float af = x[0]*wf[0] + x[1]*wf[1] + x[2]*wf[2] + x[3]*wf[3];
    float ag = x[0]*wg[0] + x[1]*wg[1] + x[2]*wg[2] + x[3]*wg[3];
    #pragma unroll
    for (int m = 32; m; m >>= 1) { af += __shfl_xor(af, m); ag += __shfl_xor(ag, m); }
    if (lane == 0) { xf[(size_t)b * TT + t] = af; xg[(size_t)b * TT + t] = ag; }
  }
}

// ---------- prep: TxP = int8 tanh, pre-swizzled per batch (32KB/batch, LDS image) ----------
// byte(b, cc=h>>4, t, e=h&15) = b*32768 + cc*2048 + ((t<<4) ^ ((cc&7)<<4)) + e
__global__ __launch_bounds__(256) void k_gemm_tx(
    const float* __restrict__ X, const float* __restrict__ W1xT,
    const float* __restrict__ b1, char* __restrict__ TxP)
{
  __shared__ float As[16][64];
  __shared__ float Bs[16][64];
  const int row0 = blockIdx.x * 64;
  const int col0 = blockIdx.y * 64;
  const int tid = threadIdx.x;
  const int tx = tid & 15, ty = tid >> 4;
  float acc[4][4] = {};
  for (int k0 = 0; k0 < 256; k0 += 16) {
    {
      const int rr = tid & 63, kk4 = (tid >> 6) << 2;
      float4 v = *(const float4*)&X[(size_t)(row0 + rr) * 256 + k0 + kk4];
      As[kk4 + 0][rr] = v.x; As[kk4 + 1][rr] = v.y;
      As[kk4 + 2][rr] = v.z; As[kk4 + 3][rr] = v.w;
    }
    {
      const int cc = tid & 63, kb = tid >> 6;
      #pragma unroll
      for (int j = 0; j < 4; ++j)
        Bs[kb + 4 * j][cc] = W1xT[(size_t)(k0 + kb + 4 * j) * 256 + col0 + cc];
    }
    __syncthreads();
    #pragma unroll
    for (int kk = 0; kk < 16; ++kk) {
      float4 a4 = *(const float4*)&As[kk][ty << 2];
      float4 b4 = *(const float4*)&Bs[kk][tx << 2];
      float av[4] = {a4.x, a4.y, a4.z, a4.w};
      float bv[4] = {b4.x, b4.y, b4.z, b4.w};
      #pragma unroll
      for (int i = 0; i < 4; ++i)
        #pragma unroll
        for (int j = 0; j < 4; ++j)
          acc[i][j] = fmaf(av[i], bv[j], acc[i][j]);
    }
    __syncthreads();
  }
  const int c = col0 + (tx << 2);
  const int ccf = c >> 4, ef = c & 15;
  #pragma unroll
  for (int i = 0; i < 4; ++i) {
    const int r = row0 + (ty << 2) + i;
    const int b = r / TT, t = r % TT;
    uchar4 o;
    o.x = (unsigned char)(char)rintf(tanhf(acc[i][0] + b1[c + 0]) * 127.f);
    o.y = (unsigned char)(char)rintf(tanhf(acc[i][1] + b1[c + 1]) * 127.f);
    o.z = (unsigned char)(char)rintf(tanhf(acc[i][2] + b1[c + 2]) * 127.f);
    o.w = (unsigned char)(char)rintf(tanhf(acc[i][3] + b1[c + 3]) * 127.f);
    *(uchar4*)&TxP[(size_t)b * 32768 + ccf * 2048 + (((t << 4) ^ ((ccf & 7) << 4))) + ef] = o;
  }
}

// ---------- main: 256 blocks x 1024 threads; Tx fully LDS-resident; weights via VGPR stream ----------
__global__ __launch_bounds__(1024, 4) void k_main(
    const char* __restrict__ TxP,
    const unsigned short* __restrict__ WP,
    const float* __restrict__ xf,
    const float* __restrict__ xg,
    const float* __restrict__ yprev,
    const float* __restrict__ W2,
    const float* __restrict__ Wih,
    const float* __restrict__ bih,
    const float* __restrict__ bhh,
    const float* __restrict__ fcW,
    const float* __restrict__ fcb,
    const float* __restrict__ fcfW,
    const float* __restrict__ fcfb,
    float* __restrict__ out)
{
  __shared__ __align__(16) char TxL[131072];        // full 4-batch int8 Tx slice (swizzled)
  __shared__ __align__(16) char dcA8[9 * 1040];     // rows 0-3 hi, 4-7 lo, 8 = zeros
  __shared__ __align__(16) float us4[1024];         // [b][hblk][16] with group-XOR layout
  __shared__ __align__(16) float sc[4][128];
  __shared__ __align__(16) float gts[4][1024];
  __shared__ float ytil[4];
  __shared__ float sg_s[4];

  const int tid = threadIdx.x;
  const int lane = tid & 63;
  const int w = tid >> 6;          // wave 0..15
  const int bb = tid >> 8;         // 0..3
  const int hq = tid & 255;        // 0..255
  const int b0 = blockIdx.x << 2;
  const int bq = w >> 2;
  const int cc = lane & 15;
  const int g4 = lane >> 4;

  for (int i = tid; i < 9 * 1040 / 2; i += 1024)
    ((unsigned short*)dcA8)[i] = 0;
  const float fcw256 = fcW[256];
  const float fcb0 = fcb[0];
  const float fcfb0 = fcfb[0];
  float creg = 0.f, dreg = 0.f;

  const int wlo = w * 1024 + lane * 16;
  // stage TxL once (pre-swizzled image; linear DMA)
  {
    const char* src = TxP + (size_t)b0 * 32768;
    #pragma unroll
    for (int i = 0; i < 8; ++i)
      __builtin_amdgcn_global_load_lds((const unsigned int*)(src + (size_t)i * 16384 + wlo),
                                       (unsigned int*)(TxL + i * 16384 + w * 1024), 16, 0, 0);
  }
  const char* wb = (const char*)WP + wlo;           // per-lane weight base; chunk stride 16384
  s8v wv0 = *(const s8v*)(wb);
  s8v wv1 = *(const s8v*)(wb + 16384);
  s8v wv2 = *(const s8v*)(wb + 2 * 16384);

  const int arow = lane & 15;
  const int rowi = arow < 8 ? arow : 8;
  const char* arbase = dcA8 + rowi * 1040;
  const int sx4 = (arow & 7) << 4;
  const int g16 = g4 << 4;
  const char* txl = TxL + bq * 32768 + cc * 2048;
  const int ccx = (cc & 7) << 4;

  asm volatile("s_waitcnt vmcnt(0) lgkmcnt(0)" ::: "memory");
  __builtin_amdgcn_s_barrier();

  for (int t = 0; t < TT; ++t) {
    // ===== A: MFMA  u = [d,c]·W1dc^T ; g = d·Whh^T (VGPR weight stream, depth-3 rotation) =====
    {
      f4v au0 = {0.f,0.f,0.f,0.f}, au1 = au0;
      f4v ag0 = au0, ag1 = au0, ag2 = au0, ag3 = au0;
      #define PROC(F, BC) { \
        const int kt_ = ((F) < 16) ? (F) : ((F) & 7); \
        s8v av_ = *(const s8v*)(arbase + ((kt_ * 64 + g16) ^ sx4)); \
        if ((F) < 16) { if ((F) & 1) au1 = mfma16(av_, BC, au1); else au0 = mfma16(av_, BC, au0); } \
        else if ((F) < 24) ag0 = mfma16(av_, BC, ag0); \
        else if ((F) < 32) ag1 = mfma16(av_, BC, ag1); \
        else if ((F) < 40) ag2 = mfma16(av_, BC, ag2); \
        else               ag3 = mfma16(av_, BC, ag3); }
      #pragma unroll
      for (int f3 = 0; f3 < 48; f3 += 3) {
        PROC(f3 + 0, wv0)
        wv0 = *(const s8v*)(wb + (size_t)((f3 + 3) % 48) * 16384);
        PROC(f3 + 1, wv1)
        wv1 = *(const s8v*)(wb + (size_t)((f3 + 4) % 48) * 16384);
        PROC(f3 + 2, wv2)
        wv2 = *(const s8v*)(wb + (size_t)((f3 + 5) % 48) * 16384);
      }
      #undef PROC
      f4v au = au0 + au1;
      #pragma unroll
      for (int r = 0; r < 4; ++r) {
        au[r] += __shfl_xor(au[r], 16);
        ag0[r] += __shfl_xor(ag0[r], 16);
        ag1[r] += __shfl_xor(ag1[r], 16);
        ag2[r] += __shfl_xor(ag2[r], 16);
        ag3[r] += __shfl_xor(ag3[r], 16);
      }
      if (lane < 16) {
        #pragma unroll
        for (int r = 0; r < 4; ++r)
          us4[r * 256 + w * 16 + ((((lane >> 2) ^ (w & 3)) << 2) | (lane & 3))] = tanh_f(au[r]);
        #pragma unroll
        for (int r = 0; r < 4; ++r) {
          gts[r][(w * 4 + 0) * 16 + lane] = ag0[r];
          gts[r][(w * 4 + 1) * 16 + lane] = ag1[r];
          gts[r][(w * 4 + 2) * 16 + lane] = ag2[r];
          gts[r][(w * 4 + 3) * 16 + lane] = ag3[r];
        }
      }
    }
    barrier_lgkm();

    // ===== B: scores from LDS TxL (127-folded tanh addition formula) =====
    {
      float tur[16], w2r[16], wt127[16];
      #pragma unroll
      for (int e4 = 0; e4 < 4; ++e4) {
        f4v tv = *(const f4v*)&us4[bq * 256 + cc * 16 + ((e4 ^ (cc & 3)) << 2)];
        f4v wv = *(const f4v*)&W2[cc * 16 + e4 * 4];
        #pragma unroll
        for (int j = 0; j < 4; ++j) {
          tur[e4*4+j] = tv[j];
          w2r[e4*4+j] = wv[j];
          wt127[e4*4+j] = wv[j] * tv[j] * 127.f;
        }
      }
      #pragma unroll
      for (int it = 0; it < 8; ++it) {
        const int tt = it * 16 + (w & 3) * 4 + g4;
        const int ttc = tt < 126 ? tt : 126;
        i4v dv = *(const i4v*)(txl + (((ttc << 4) ^ ccx)));
        float acc = 0.f;
        #pragma unroll
        for (int j = 0; j < 4; ++j) {
          const int d = dv[j];
          const float x0 = (float)((d << 24) >> 24);
          const float x1 = (float)((d << 16) >> 24);
          const float x2 = (float)((d << 8) >> 24);
          const float x3 = (float)(d >> 24);
          const int e = j * 4;
          acc = fmaf(fmaf(w2r[e+0], x0, wt127[e+0]), frcp(fmaf(tur[e+0], x0, 127.f)), acc);
          acc = fmaf(fmaf(w2r[e+1], x1, wt127[e+1]), frcp(fmaf(tur[e+1], x1, 127.f)), acc);
          acc = fmaf(fmaf(w2r[e+2], x2, wt127[e+2]), frcp(fmaf(tur[e+2], x2, 127.f)), acc);
          acc = fmaf(fmaf(w2r[e+3], x3, wt127[e+3]), frcp(fmaf(tur[e+3], x3, 127.f)), acc);
        }
        acc += __shfl_xor(acc, 1);
        acc += __shfl_xor(acc, 2);
        acc += __shfl_xor(acc, 4);
        acc += __shfl_xor(acc, 8);
        if (cc == 0 && tt < TT) sc[bq][tt] = acc;
      }
    }
    barrier_lgkm();

    // ===== softmax + scalar dots (waves 0..3; xf/xg/yprev from L2) =====
    if (w < 4) {
      const float s0 = sc[w][lane];
      const float s1 = (lane < 63) ? sc[w][lane + 64] : -3.0e38f;
      float mx = fmaxf(s0, s1);
      #pragma unroll
      for (int m = 32; m; m >>= 1) mx = fmaxf(mx, __shfl_xor(mx, m));
      const float p0 = fexp2((s0 - mx) * L2E);
      const float p1 = (lane < 63) ? fexp2((s1 - mx) * L2E) : 0.f;
      const float xfv0 = xf[(size_t)(b0 + w) * TT + lane];
      const float xfv1 = (lane < 63) ? xf[(size_t)(b0 + w) * TT + lane + 64] : 0.f;
      float sm = p0 + p1;
      float af = fmaf(p0, xfv0, p1 * xfv1);
      #pragma unroll
      for (int m = 32; m; m >>= 1) {
        sm += __shfl_xor(sm, m);
        af += __shfl_xor(af, m);
      }
      const float inv = frcp(sm);
      if (lane == 0)
        ytil[w] = af * inv + fcw256 * yprev[(size_t)(b0 + w) * TT + t] + fcb0;
      if (t == TT - 1) {
        const float xgv0 = xg[(size_t)(b0 + w) * TT + lane];
        const float xgv1 = (lane < 63) ? xg[(size_t)(b0 + w) * TT + lane + 64] : 0.f;
        float ag_ = fmaf(p0, xgv0, p1 * xgv1);
        #pragma unroll
        for (int m = 32; m; m >>= 1) ag_ += __shfl_xor(ag_, m);
        if (lane == 0) sg_s[w] = ag_ * inv;
      }
    }
    barrier_lgkm();

    // ===== D2/D3: gates + LSTM pointwise (weights/biases from L2; swizzled dcA writes) =====
    {
      const float yt = ytil[bb];
      const float gi = gts[bb][hq]       + yt * Wih[hq]       + bih[hq]       + bhh[hq];
      const float gf = gts[bb][hq + 256] + yt * Wih[hq + 256] + bih[hq + 256] + bhh[hq + 256];
      const float gg = gts[bb][hq + 512] + yt * Wih[hq + 512] + bih[hq + 512] + bhh[hq + 512];
      const float go = gts[bb][hq + 768] + yt * Wih[hq + 768] + bih[hq + 768] + bhh[hq + 768];
      creg = sigm(gf) * creg + sigm(gi) * tanh_f(gg);
      dreg = sigm(go) * tanh_f(creg);
      const unsigned short dh = f2bf(dreg);
      const unsigned short dl = f2bf(dreg - bf2f(dh));
      const unsigned short ch = f2bf(creg);
      const unsigned short cl = f2bf(creg - bf2f(ch));
      const int cd = 2 * hq;
      const int ccol = 512 + 2 * hq;
      const int sh = (bb & 7) << 4;
      const int sl = ((bb + 4) & 7) << 4;
      *(unsigned short*)(dcA8 + bb * 1040       + (((cd & ~15) ^ sh) | (cd & 15)))     = dh;
      *(unsigned short*)(dcA8 + (bb + 4) * 1040 + (((cd & ~15) ^ sl) | (cd & 15)))     = dl;
      *(unsigned short*)(dcA8 + bb * 1040       + (((ccol & ~15) ^ sh) | (ccol & 15))) = ch;
      *(unsigned short*)(dcA8 + (bb + 4) * 1040 + (((ccol & ~15) ^ sl) | (ccol & 15))) = cl;
    }
    barrier_lgkm();
  }

  // ---- output: y_pred = d·fcfW[0:256] + sg + fcfb ----
  ((float*)gts)[bb * 256 + hq] = dreg;
  barrier_lgkm();
  if (w < 4) {
    float a = 0.f;
    #pragma unroll
    for (int j = 0; j < 4; ++j) {
      const int m = lane + (j << 6);
      a = fmaf(((const float*)gts)[w * 256 + m], fcfW[m], a);
    }
    #pragma unroll
    for (int m = 32; m; m >>= 1) a += __shfl_xor(a, m);
    if (lane == 0) out[b0 + w] = a + sg_s[w] + fcfb0;
  }
  asm volatile("s_waitcnt vmcnt(0)" ::: "memory");
}

extern "C" void kernel_launch(void* const* d_in, const int* in_sizes, int n_in,
                              void* d_out, int out_size, void* d_ws, size_t ws_size,
                              hipStream_t stream) {
  const float* X    = (const float*)d_in[0];
  const float* yprev= (const float*)d_in[1];
  const float* W1   = (const float*)d_in[2];
  const float* b1   = (const float*)d_in[3];
  const float* W2   = (const float*)d_in[4];
  // d_in[5] = attn_b2: softmax-invariant, unused
  const float* Wih  = (const float*)d_in[6];
  const float* Whh  = (const float*)d_in[7];
  const float* bih  = (const float*)d_in[8];
  const float* bhh  = (const float*)d_in[9];
  const float* fcW  = (const float*)d_in[10];
  const float* fcb  = (const float*)d_in[11];
  const float* fcfW = (const float*)d_in[12];
  const float* fcfb = (const float*)d_in[13];
  float* out = (float*)d_out;

  size_t off = 0;
  char* base = (char*)d_ws;
  auto alloc = [&](size_t bytes) -> void* {
    void* p = base + off;
    off += (bytes + 255) & ~(size_t)255;
    return p;
  };
  char* TxP            = (char*)alloc((size_t)1024 * 32768);
  unsigned short* WP   = (unsigned short*)alloc((size_t)48 * 16384);
  float* W1xT          = (float*)alloc((size_t)256 * 256 * 4);
  float* xf            = (float*)alloc((size_t)1024 * TT * 4);
  float* xg            = (float*)alloc((size_t)1024 * TT * 4);
  (void)in_sizes; (void)n_in; (void)out_size; (void)ws_size;

  k_pack_w1dc<<<64, 256, 0, stream>>>(W1, WP);
  k_pack_whh<<<128, 256, 0, stream>>>(Whh, WP);
  k_tr_w1x<<<256, 256, 0, stream>>>(W1, W1xT);
  k_xfg<<<1024, 256, 0, stream>>>(X, fcW, fcfW, xf, xg);
  dim3 gg(2032, 4);
  k_gemm_tx<<<gg, 256, 0, stream>>>(X, W1xT, b1, TxP);
  k_main<<<256, 1024, 0, stream>>>(TxP, WP, xf, xg, yprev, W2,
                                   Wih, bih, bhh, fcW, fcb, fcfW, fcfb, out);
}

// Round 19
// 4171.872 us; speedup vs baseline: 1.2398x; 1.2398x over previous
//
#include <hip/hip_runtime.h>
#include <hip/hip_bf16.h>

#define TT 127
#define L2E 1.4426950408889634f

typedef __attribute__((ext_vector_type(8))) short s8v;
typedef __attribute__((ext_vector_type(4))) float f4v;
typedef __attribute__((ext_vector_type(4))) int i4v;

__device__ __forceinline__ float bf2f(unsigned short u){
  union { unsigned int i; float f; } v; v.i = ((unsigned int)u) << 16; return v.f;
}
__device__ __forceinline__ unsigned short f2bf(float f){
  union { float f; unsigned int i; } v; v.f = f;
  unsigned int r = v.i + 0x7FFFu + ((v.i >> 16) & 1u);
  return (unsigned short)(r >> 16);
}
__device__ __forceinline__ float fexp2(float x){ return __builtin_amdgcn_exp2f(x); }
__device__ __forceinline__ float frcp(float x){ return __builtin_amdgcn_rcpf(x); }
__device__ __forceinline__ float sigm(float x){
  return frcp(1.f + fexp2(-L2E * x));
}
__device__ __forceinline__ float tanh_f(float x){
  return 1.f - 2.f * frcp(1.f + fexp2(2.f * L2E * x));
}
__device__ __forceinline__ f4v mfma16(s8v a, s8v b, f4v c){
  return __builtin_amdgcn_mfma_f32_16x16x32_bf16(a, b, c, 0, 0, 0);
}
__device__ __forceinline__ void barrier_lgkm(){
  asm volatile("s_waitcnt lgkmcnt(0)" ::: "memory");
  __builtin_amdgcn_s_barrier();
}

// ---------- prep: pack weights chunk-major for the LDS ring ----------
__global__ void k_pack_w1dc(const float* __restrict__ W1, unsigned short* __restrict__ WP){
  int n = blockIdx.x * 256 + threadIdx.x;   // 16384 = [kt][w][lane]
  int lane = n & 63, w = (n >> 6) & 15, kt = n >> 10;
  int h = w * 16 + (lane & 15);
  int i0 = kt * 32 + (lane >> 4) * 8;
  #pragma unroll
  for (int j = 0; j < 8; ++j)
    WP[(size_t)n * 8 + j] = f2bf(W1[h * 768 + i0 + j]);
}
__global__ void k_pack_whh(const float* __restrict__ Whh, unsigned short* __restrict__ WP){
  int n = blockIdx.x * 256 + threadIdx.x;   // 32768 = [f][w][lane]
  int lane = n & 63, w = (n >> 6) & 15, f = n >> 10;
  int ct = f >> 3, kt = f & 7;
  int g = (w * 4 + ct) * 16 + (lane & 15);
  int i0 = kt * 32 + (lane >> 4) * 8;
  #pragma unroll
  for (int j = 0; j < 8; ++j)
    WP[131072 + (size_t)n * 8 + j] = f2bf(Whh[g * 256 + i0 + j]);
}

__global__ void k_tr_w1x(const float* __restrict__ W1, float* __restrict__ W1xT){
  int idx = blockIdx.x * 256 + threadIdx.x;   // 256*256
  int k = idx >> 8, h = idx & 255;
  W1xT[idx] = W1[h * 768 + 512 + k];
}

// ---------- prep: xf[b,t] = X[b,t,:]·fcW[0:256], xg[b,t] = X[b,t,:]·fcfW[256:512] ----------
__global__ void k_xfg(const float* __restrict__ X, const float* __restrict__ fcW,
                      const float* __restrict__ fcfW,
                      float* __restrict__ xf, float* __restrict__ xg){
  const int b = blockIdx.x;
  const int w = threadIdx.x >> 6, lane = threadIdx.x & 63;
  f4v wf = *(const f4v*)&fcW[lane * 4];
  f4v wg = *(const f4v*)&fcfW[256 + lane * 4];
  for (int t = w; t < TT; t += 4) {
    f4v x = *(const f4v*)&X[((size_t)b * TT + t) * 256 + lane * 4];
    float af = x[0]*wf[0] + x[1]*wf[1] + x[2]*wf[2] + x[3]*wf[3];
    float ag = x[0]*wg[0] + x[1]*wg[1] + x[2]*wg[2] + x[3]*wg[3];
    #pragma unroll
    for (int m = 32; m; m >>= 1) { af += __shfl_xor(af, m); ag += __shfl_xor(ag, m); }
    if (lane == 0) { xf[(size_t)b * TT + t] = af; xg[(size_t)b * TT + t] = ag; }
  }
}

// ---------- prep: Tx8[b,t,h] = int8( round(127*tanh(X·W1x + b1)) ) ----------
__global__ __launch_bounds__(256) void k_gemm_tx(
    const float* __restrict__ X, const float* __restrict__ W1xT,
    const float* __restrict__ b1, char* __restrict__ Tx8)
{
  __shared__ float As[16][64];
  __shared__ float Bs[16][64];
  const int row0 = blockIdx.x * 64;
  const int col0 = blockIdx.y * 64;
  const int tid = threadIdx.x;
  const int tx = tid & 15, ty = tid >> 4;
  float acc[4][4] = {};
  for (int k0 = 0; k0 < 256; k0 += 16) {
    {
      const int rr = tid & 63, kk4 = (tid >> 6) << 2;
      float4 v = *(const float4*)&X[(size_t)(row0 + rr) * 256 + k0 + kk4];
      As[kk4 + 0][rr] = v.x; As[kk4 + 1][rr] = v.y;
      As[kk4 + 2][rr] = v.z; As[kk4 + 3][rr] = v.w;
    }
    {
      const int cc = tid & 63, kb = tid >> 6;
      #pragma unroll
      for (int j = 0; j < 4; ++j)
        Bs[kb + 4 * j][cc] = W1xT[(size_t)(k0 + kb + 4 * j) * 256 + col0 + cc];
    }
    __syncthreads();
    #pragma unroll
    for (int kk = 0; kk < 16; ++kk) {
      float4 a4 = *(const float4*)&As[kk][ty << 2];
      float4 b4 = *(const float4*)&Bs[kk][tx << 2];
      float av[4] = {a4.x, a4.y, a4.z, a4.w};
      float bv[4] = {b4.x, b4.y, b4.z, b4.w};
      #pragma unroll
      for (int i = 0; i < 4; ++i)
        #pragma unroll
        for (int j = 0; j < 4; ++j)
          acc[i][j] = fmaf(av[i], bv[j], acc[i][j]);
    }
    __syncthreads();
  }
  const int c = col0 + (tx << 2);
  #pragma unroll
  for (int i = 0; i < 4; ++i) {
    const int r = row0 + (ty << 2) + i;
    uchar4 o;
    o.x = (unsigned char)(char)rintf(tanhf(acc[i][0] + b1[c + 0]) * 127.f);
    o.y = (unsigned char)(char)rintf(tanhf(acc[i][1] + b1[c + 1]) * 127.f);
    o.z = (unsigned char)(char)rintf(tanhf(acc[i][2] + b1[c + 2]) * 127.f);
    o.w = (unsigned char)(char)rintf(tanhf(acc[i][3] + b1[c + 3]) * 127.f);
    *(uchar4*)&Tx8[(size_t)r * 256 + c] = o;
  }
}

// ---------- main: 256 blocks x 1024 threads, 4 batch/block; int8 Tx, swizzled dcA ----------
__global__ __launch_bounds__(1024, 4) void k_main(
    const char* __restrict__ Tx8,
    const unsigned short* __restrict__ WP,
    const float* __restrict__ xf,
    const float* __restrict__ xg,
    const float* __restrict__ yprev,
    const float* __restrict__ W2,
    const float* __restrict__ Wih,
    const float* __restrict__ bih,
    const float* __restrict__ bhh,
    const float* __restrict__ fcW,
    const float* __restrict__ fcb,
    const float* __restrict__ fcfW,
    const float* __restrict__ fcfb,
    float* __restrict__ out)
{
  __shared__ __align__(16) char wring[6 * 16384];            // 96KB weight ring
  // dcA: 16 rows x 1152B (stride ≡ 0 mod 128B); XOR-swizzled slots; rows 8-15 zero pad
  __shared__ __align__(16) char dcA8[16 * 1152];
  __shared__ __align__(16) float us_s[4][320];               // padded: idx = w*20 + lane
  __shared__ __align__(16) float sc[4][128];
  __shared__ __align__(16) float gts[4][1024];
  __shared__ float w2s[256];
  __shared__ float fcfw_s[256];
  __shared__ float wih_s[1024];
  __shared__ float bsum_s[1024];
  __shared__ float yp_s[4][128];
  __shared__ float xf_s[4][128];
  __shared__ float xg_s[4][128];
  __shared__ float ytil[4];
  __shared__ float sg_s[4];

  const int tid = threadIdx.x;
  const int lane = tid & 63;
  const int w = tid >> 6;          // wave 0..15
  const int bb = tid >> 8;         // 0..3
  const int hq = tid & 255;        // 0..255
  const int b0 = blockIdx.x << 2;
  const int bq = w >> 2;
  const int cc = lane & 15;
  const int g4 = lane >> 4;

  if (tid < 256) w2s[tid] = W2[tid];
  if (tid >= 256 && tid < 512) fcfw_s[tid - 256] = fcfW[tid - 256];
  wih_s[tid] = Wih[tid];
  bsum_s[tid] = bih[tid] + bhh[tid];
  if (tid < 512 && (tid & 127) < TT)
    yp_s[tid >> 7][tid & 127] = yprev[(size_t)(b0 + (tid >> 7)) * TT + (tid & 127)];
  if (tid >= 512) {
    const int r = (tid - 512) >> 7, c = tid & 127;
    float vf = 0.f, vg = 0.f;
    if (c < TT) {
      vf = xf[(size_t)(b0 + r) * TT + c];
      vg = xg[(size_t)(b0 + r) * TT + c];
    }
    xf_s[r][c] = vf;
    xg_s[r][c] = vg;
  }
  for (int i = tid; i < 16 * 1152 / 2; i += 1024)
    ((unsigned short*)dcA8)[i] = 0;
  const float fcw256 = fcW[256];
  const float fcb0 = fcb[0];
  const float fcfb0 = fcfb[0];
  float creg = 0.f, dreg = 0.f;
  barrier_lgkm();

  const int arow = lane & 15;
  const char* arbase = dcA8 + arow * 1152;
  const int sx4 = (arow & 7) << 4;             // XOR swizzle on 16B-slot bits
  const int g16 = (lane >> 4) << 4;
  const int wlo = w * 1024 + lane * 16;
  const char* WPc = (const char*)WP;
  const char* wslice = wring + wlo;
  char* wdst = wring + w * 1024;

  // prologue: stage chunks 0..5 into ring slots 0..5
  #pragma unroll
  for (int F = 0; F < 6; ++F) {
    __builtin_amdgcn_global_load_lds((const unsigned int*)(WPc + (size_t)F * 16384 + wlo),
                                     (unsigned int*)(wdst + F * 16384), 16, 0, 0);
  }
  asm volatile("s_waitcnt vmcnt(5)" ::: "memory");
  __builtin_amdgcn_sched_barrier(0);
  s8v bnext = *(const s8v*)(wslice);

  for (int t = 0; t < TT; ++t) {
    // ===== A: MFMA  u = [d,c]·W1dc^T ; g = d·Whh^T (ring-fed, period-48) =====
    {
      f4v au0 = {0.f,0.f,0.f,0.f}, au1 = au0;
      f4v ag0 = au0, ag1 = au0, ag2 = au0, ag3 = au0;
      #pragma unroll
      for (int f = 0; f < 48; ++f) {
        s8v bcur = bnext;
        asm volatile("s_waitcnt vmcnt(4)" ::: "memory");
        __builtin_amdgcn_sched_barrier(0);
        bnext = *(const s8v*)(wslice + (((f + 1) % 6) * 16384));
        const int kt = (f < 16) ? f : (f & 7);
        s8v av = *(const s8v*)(arbase + ((kt * 64 + g16) ^ sx4));   // swizzled read
        if (f < 16) {
          if (f & 1) au1 = mfma16(av, bcur, au1);
          else       au0 = mfma16(av, bcur, au0);
        } else if (f < 24) {
          ag0 = mfma16(av, bcur, ag0);
        } else if (f < 32) {
          ag1 = mfma16(av, bcur, ag1);
        } else if (f < 40) {
          ag2 = mfma16(av, bcur, ag2);
        } else {
          ag3 = mfma16(av, bcur, ag3);
        }
        const int nf = (f + 6) % 48;
        __builtin_amdgcn_global_load_lds((const unsigned int*)(WPc + (size_t)nf * 16384 + wlo),
                                         (unsigned int*)(wdst + (f % 6) * 16384), 16, 0, 0);
      }
      f4v au = au0 + au1;
      #pragma unroll
      for (int r = 0; r < 4; ++r) {
        au[r] += __shfl_xor(au[r], 16);
        ag0[r] += __shfl_xor(ag0[r], 16);
        ag1[r] += __shfl_xor(ag1[r], 16);
        ag2[r] += __shfl_xor(ag2[r], 16);
        ag3[r] += __shfl_xor(ag3[r], 16);
      }
      if (lane < 16) {
        const int hp = w * 20 + lane;
        #pragma unroll
        for (int r = 0; r < 4; ++r)
          us_s[r][hp] = tanh_f(au[r]);
        #pragma unroll
        for (int r = 0; r < 4; ++r) {
          gts[r][(w * 4 + 0) * 16 + lane] = ag0[r];
          gts[r][(w * 4 + 1) * 16 + lane] = ag1[r];
          gts[r][(w * 4 + 2) * 16 + lane] = ag2[r];
          gts[r][(w * 4 + 3) * 16 + lane] = ag3[r];
        }
      }
    }
    barrier_lgkm();

    // ===== B: scores, streaming int8 Tx (127-folded tanh addition formula) =====
    {
      float tur[16], w2r[16], wt127[16];
      #pragma unroll
      for (int e4 = 0; e4 < 4; ++e4) {
        f4v tv = *(const f4v*)&us_s[bq][cc * 20 + e4 * 4];
        f4v wv = *(const f4v*)&w2s[cc * 16 + e4 * 4];
        #pragma unroll
        for (int j = 0; j < 4; ++j) {
          tur[e4*4+j] = tv[j];
          w2r[e4*4+j] = wv[j];
          wt127[e4*4+j] = wv[j] * tv[j] * 127.f;
        }
      }
      const char* txb = &Tx8[((size_t)(b0 + bq) * TT) * 256 + cc * 16];
      #pragma unroll
      for (int it = 0; it < 8; ++it) {
        const int tt = it * 16 + (w & 3) * 4 + g4;
        const int ttc = tt < 126 ? tt : 126;
        i4v dv = *(const i4v*)(txb + (size_t)ttc * 256);
        float acc = 0.f;
        #pragma unroll
        for (int j = 0; j < 4; ++j) {
          const int d = dv[j];
          const float x0 = (float)((d << 24) >> 24);
          const float x1 = (float)((d << 16) >> 24);
          const float x2 = (float)((d << 8) >> 24);
          const float x3 = (float)(d >> 24);
          const int e = j * 4;
          acc = fmaf(fmaf(w2r[e+0], x0, wt127[e+0]), frcp(fmaf(tur[e+0], x0, 127.f)), acc);
          acc = fmaf(fmaf(w2r[e+1], x1, wt127[e+1]), frcp(fmaf(tur[e+1], x1, 127.f)), acc);
          acc = fmaf(fmaf(w2r[e+2], x2, wt127[e+2]), frcp(fmaf(tur[e+2], x2, 127.f)), acc);
          acc = fmaf(fmaf(w2r[e+3], x3, wt127[e+3]), frcp(fmaf(tur[e+3], x3, 127.f)), acc);
        }
        acc += __shfl_xor(acc, 1);
        acc += __shfl_xor(acc, 2);
        acc += __shfl_xor(acc, 4);
        acc += __shfl_xor(acc, 8);
        if (cc == 0 && tt < TT) sc[bq][tt] = acc;
      }
    }
    barrier_lgkm();

    // ===== fused softmax + scalar dot (waves 0..3): ytil, and sg at last step =====
    if (w < 4) {
      const float s0 = sc[w][lane];
      const float s1 = (lane < 63) ? sc[w][lane + 64] : -3.0e38f;
      float mx = fmaxf(s0, s1);
      #pragma unroll
      for (int m = 32; m; m >>= 1) mx = fmaxf(mx, __shfl_xor(mx, m));
      const float p0 = fexp2((s0 - mx) * L2E);
      const float p1 = (lane < 63) ? fexp2((s1 - mx) * L2E) : 0.f;
      float sm = p0 + p1;
      float af = fmaf(p0, xf_s[w][lane], p1 * xf_s[w][(lane + 64) & 127]);
      #pragma unroll
      for (int m = 32; m; m >>= 1) {
        sm += __shfl_xor(sm, m);
        af += __shfl_xor(af, m);
      }
      const float inv = frcp(sm);
      if (lane == 0)
        ytil[w] = af * inv + fcw256 * yp_s[w][t] + fcb0;
      if (t == TT - 1) {
        float ag_ = fmaf(p0, xg_s[w][lane], p1 * xg_s[w][(lane + 64) & 127]);
        #pragma unroll
        for (int m = 32; m; m >>= 1) ag_ += __shfl_xor(ag_, m);
        if (lane == 0) sg_s[w] = ag_ * inv;
      }
    }
    barrier_lgkm();

    // ===== D2/D3: gates + LSTM pointwise (swizzled dcA writes) =====
    {
      const float yt = ytil[bb];
      const float gi = gts[bb][hq]       + yt * wih_s[hq]       + bsum_s[hq];
      const float gf = gts[bb][hq + 256] + yt * wih_s[hq + 256] + bsum_s[hq + 256];
      const float gg = gts[bb][hq + 512] + yt * wih_s[hq + 512] + bsum_s[hq + 512];
      const float go = gts[bb][hq + 768] + yt * wih_s[hq + 768] + bsum_s[hq + 768];
      creg = sigm(gf) * creg + sigm(gi) * tanh_f(gg);
      dreg = sigm(go) * tanh_f(creg);
      const unsigned short dh = f2bf(dreg);
      const unsigned short dl = f2bf(dreg - bf2f(dh));
      const unsigned short ch = f2bf(creg);
      const unsigned short cl = f2bf(creg - bf2f(ch));
      const int cd = 2 * hq;         // d columns: bytes 0..511
      const int ccol = 512 + 2 * hq; // c columns: bytes 512..1023
      const int sh = (bb & 7) << 4;
      const int sl = ((bb + 4) & 7) << 4;
      *(unsigned short*)(dcA8 + bb * 1152       + (((cd & ~15) ^ sh) | (cd & 15)))   = dh;
      *(unsigned short*)(dcA8 + (bb + 4) * 1152 + (((cd & ~15) ^ sl) | (cd & 15)))   = dl;
      *(unsigned short*)(dcA8 + bb * 1152       + (((ccol & ~15) ^ sh) | (ccol & 15))) = ch;
      *(unsigned short*)(dcA8 + (bb + 4) * 1152 + (((ccol & ~15) ^ sl) | (ccol & 15))) = cl;
    }
    barrier_lgkm();
  }

  // ---- output: y_pred = d·fcfW[0:256] + sg + fcfb ----
  us_s[bb][hq] = dreg;
  barrier_lgkm();
  if (w < 4) {
    float a = 0.f;
    #pragma unroll
    for (int j = 0; j < 4; ++j) {
      const int m = lane + (j << 6);
      a = fmaf(us_s[w][m], fcfw_s[m], a);
    }
    #pragma unroll
    for (int m = 32; m; m >>= 1) a += __shfl_xor(a, m);
    if (lane == 0) out[b0 + w] = a + sg_s[w] + fcfb0;
  }
  asm volatile("s_waitcnt vmcnt(0)" ::: "memory");
}

extern "C" void kernel_launch(void* const* d_in, const int* in_sizes, int n_in,
                              void* d_out, int out_size, void* d_ws, size_t ws_size,
                              hipStream_t stream) {
  const float* X    = (const float*)d_in[0];
  const float* yprev= (const float*)d_in[1];
  const float* W1   = (const float*)d_in[2];
  const float* b1   = (const float*)d_in[3];
  const float* W2   = (const float*)d_in[4];
  // d_in[5] = attn_b2: softmax-invariant, unused
  const float* Wih  = (const float*)d_in[6];
  const float* Whh  = (const float*)d_in[7];
  const float* bih  = (const float*)d_in[8];
  const float* bhh  = (const float*)d_in[9];
  const float* fcW  = (const float*)d_in[10];
  const float* fcb  = (const float*)d_in[11];
  const float* fcfW = (const float*)d_in[12];
  const float* fcfb = (const float*)d_in[13];
  float* out = (float*)d_out;

  size_t off = 0;
  char* base = (char*)d_ws;
  auto alloc = [&](size_t bytes) -> void* {
    void* p = base + off;
    off += (bytes + 255) & ~(size_t)255;
    return p;
  };
  char* Tx8            = (char*)alloc((size_t)1024 * TT * 256);
  unsigned short* WP   = (unsigned short*)alloc((size_t)48 * 16384);
  float* W1xT          = (float*)alloc((size_t)256 * 256 * 4);
  float* xf            = (float*)alloc((size_t)1024 * TT * 4);
  float* xg            = (float*)alloc((size_t)1024 * TT * 4);
  (void)in_sizes; (void)n_in; (void)out_size; (void)ws_size;

  k_pack_w1dc<<<64, 256, 0, stream>>>(W1, WP);
  k_pack_whh<<<128, 256, 0, stream>>>(Whh, WP);
  k_tr_w1x<<<256, 256, 0, stream>>>(W1, W1xT);
  k_xfg<<<1024, 256, 0, stream>>>(X, fcW, fcfW, xf, xg);
  dim3 gg(2032, 4);
  k_gemm_tx<<<gg, 256, 0, stream>>>(X, W1xT, b1, Tx8);
  k_main<<<256, 1024, 0, stream>>>(Tx8, WP, xf, xg, yprev, W2,
                                   Wih, bih, bhh, fcW, fcb, fcfW, fcfb, out);
}